// Round 13
// baseline (211.058 us; speedup 1.0000x reference)
//
#include <hip/hip_runtime.h>

#define RR 12
#define PD 25
#define PP 625
#define HH 30
#define WW 30
#define HWD 900
#define CD 512
#define BD 8
#define TD 4
#define CSTRIDE 628            // 625 + 3 pad
#define ROWPKB 32768           // BYTES per packed (plane,row): 16ks * 2piece * 64lane * 16B
#define QSCALE 16129.0f        // 127*127
#define EXPK (512.0f / QSCALE) // folded exp scale

typedef __attribute__((ext_vector_type(4))) int i32x4;
typedef __attribute__((ext_vector_type(16))) int i32x16;

// relu + L2-normalize over C, then quantize to 2-piece int8 fixed point:
//   a ~= (A1 + A2/254)/127,  A1 in [0,127], A2 in [-127,127]
// packed in 32x32x32-i8 MFMA fragment-major layout:
//   [plane][row][ks(16)][piece(2)][lane(64)][16 bytes]
//   element (pix x = lane&31, k = ks*32 + (lane>>5)*16 + j)
// plane 0..7: patch -> outA ; plane 8..39: video bt -> outB
__global__ __launch_bounds__(256) void norm_pack_kernel(const float* __restrict__ inP,
                                                        const float* __restrict__ inV,
                                                        unsigned char* __restrict__ outA,
                                                        unsigned char* __restrict__ outB) {
    int row = blockIdx.x;    // 0..29
    int plane = blockIdx.y;  // 0..39
    const float* in;
    size_t base;
    int c_stride;
    unsigned char* ob;
    if (plane < 8) {
        in = inP; c_stride = HWD;
        base = (size_t)plane * CD * HWD + row * WW;
        ob = outA + (size_t)(plane * 30 + row) * ROWPKB;
    } else {
        int bt = plane - 8;
        int b = bt >> 2, t = bt & 3;
        in = inV; c_stride = TD * HWD;
        base = (size_t)b * CD * (TD * HWD) + (size_t)t * HWD + row * WW;
        ob = outB + (size_t)(bt * 30 + row) * ROWPKB;
    }
    __shared__ float tile[30][516];
    __shared__ float inv[30];
    int tid = threadIdx.x;
    // float2 loads: 30 pixels = 15 float2 per c-row (8-B aligned: row*120 % 8 == 0)
    for (int it = 0; it < 32; ++it) {
        int lin = it * 256 + tid;     // 8192 slots = 512 c * 16 pg (pg 15 idle)
        int c = lin >> 4, pg = lin & 15;
        if (pg < 15) {
            const float2 v = *reinterpret_cast<const float2*>(
                &in[base + (size_t)c * c_stride + pg * 2]);
            tile[pg * 2][c] = fmaxf(v.x, 0.f);
            tile[pg * 2 + 1][c] = fmaxf(v.y, 0.f);
        }
    }
    __syncthreads();
    if ((tid >> 3) < 30) {
        int p = tid >> 3, s8 = tid & 7;
        float acc = 0.f;
#pragma unroll
        for (int j = 0; j < 16; ++j) {
            const float4 v = *reinterpret_cast<const float4*>(&tile[p][(s8 + j * 8) * 4]);
            acc += v.x * v.x + v.y * v.y + v.z * v.z + v.w * v.w;
        }
        acc += __shfl_xor(acc, 1);
        acc += __shfl_xor(acc, 2);
        acc += __shfl_xor(acc, 4);
        if (s8 == 0) inv[p] = 1.0f / fmaxf(sqrtf(acc), 1e-12f);
    }
    __syncthreads();
    for (int sl = tid; sl < 1024; sl += 256) {   // sl = ks*64 + lane
        int ks = sl >> 6, ln = sl & 63;
        int x = ln & 31;
        if (x > 29) x = 29;                       // pad lanes (guarded in corr)
        int kb = ks * 32 + (ln >> 5) * 16;
        float iv = inv[x];
        union { signed char c[16]; i32x4 v; } p1, p2;
#pragma unroll
        for (int j = 0; j < 16; ++j) {
            float nv = tile[x][kb + j] * iv;      // in [0,1]
            float s1 = rintf(nv * 127.f);
            float r = nv * 127.f - s1;
            float s2 = rintf(r * 254.f);
            p1.c[j] = (signed char)(int)s1;
            p2.c[j] = (signed char)(int)s2;
        }
        *(i32x4*)(ob + (size_t)ks * 2048 + ln * 16) = p1.v;
        *(i32x4*)(ob + (size_t)ks * 2048 + 1024 + ln * 16) = p2.v;
    }
}

// 1D grid of 960, XCD-bijective swizzle: xcd r owns b=r (bt in 4r..4r+3).
// 1024 thr = 16 waves = 8 PAIRS. Pair p owns dh slots (stride 8); the two waves
// of a pair read the SAME full B row (2nd read hits per-CU L1 -> L2 traffic
// halved) and each applies ONE A piece: wave even: a1*(b1,b2) -> s11 + s12/254;
// wave odd: a2*(b1,b2) -> (s21 + s22/254)/254. Partials merge via ds_add_f32.
// A-row staged in LDS. Output via non-temporal stores.
__global__ __launch_bounds__(1024, 4) void corr_kernel(
    const unsigned char* __restrict__ Apk, const unsigned char* __restrict__ Bpk,
    float* __restrict__ out) {
    int gid = blockIdx.x;
    int r = gid & 7;          // target XCD
    int x_ = gid >> 3;        // 0..119
    int btl = x_ / 30;
    int h = x_ - btl * 30;
    int bt = r * 4 + btl;
    int b = r;

    __shared__ __attribute__((aligned(16))) float corr[HH * CSTRIDE];
    __shared__ unsigned char alds[ROWPKB];
    __shared__ float is_lds[HH];
    int tid = threadIdx.x;
    int wid = tid >> 6, lane = tid & 63;
    int wa = wid & 1;         // A-piece role
    int pr = wid >> 1;        // pair index 0..7

    {
        float4 z = {0.f, 0.f, 0.f, 0.f};
        float4* cz = (float4*)corr;
        for (int i = tid; i < (HH * CSTRIDE) / 4; i += 1024) cz[i] = z;
    }
    // stage A row (32 KB) into LDS, linear copy
    {
        const uint4* src = (const uint4*)(Apk + (size_t)(b * 30 + h) * ROWPKB);
        uint4* dst = (uint4*)alds;
#pragma unroll
        for (int i = 0; i < 2; ++i) dst[i * 1024 + tid] = src[i * 1024 + tid];
    }
    const unsigned char* bplane = Bpk + (size_t)bt * 30 * ROWPKB + lane * 16;
    int dh_lo = max(0, RR - h);
    int dh_hi = min(PD - 1, HH - 1 + RR - h);
    __syncthreads();  // corr zeroed + A staged

    const unsigned char* albase = alds + lane * 16 + wa * 1024;  // a1 or a2
    float wscale = wa ? (1.0f / 254.0f) : 1.0f;
    int x = lane & 31;
    int rbase = 4 * (lane >> 5);

    for (int dh = dh_lo + pr; dh <= dh_hi; dh += 8) {
        int y = h + dh - RR;
        const unsigned char* bbase = bplane + (size_t)y * ROWPKB;
        i32x16 sA, sB;
#pragma unroll
        for (int i = 0; i < 16; ++i) { sA[i] = 0; sB[i] = 0; }
#pragma unroll 8
        for (int ks = 0; ks < 16; ++ks) {
            i32x4 a = *(const i32x4*)(albase + ks * 2048);
            i32x4 b1 = *(const i32x4*)(bbase + ks * 2048);
            i32x4 b2 = *(const i32x4*)(bbase + ks * 2048 + 1024);
            sA = __builtin_amdgcn_mfma_i32_32x32x32_i8(a, b1, sA, 0, 0, 0);
            sB = __builtin_amdgcn_mfma_i32_32x32x32_i8(a, b2, sB, 0, 0, 0);
        }
        if (x < 30) {
#pragma unroll
            for (int rr = 0; rr < 16; ++rr) {
                int w = (rr & 3) + 8 * (rr >> 2) + rbase;  // C layout: col=lane&31
                int dw = x - w + RR;
                if (w < 30 && (unsigned)dw < (unsigned)PD) {
                    float val = fmaf((float)sB[rr], 1.0f / 254.0f, (float)sA[rr]) * wscale;
                    atomicAdd(&corr[w * CSTRIDE + dh * PD + dw], val);
                }
            }
        }
    }
    __syncthreads();

    // per-pixel softmax over 625 offsets (zeros present for OOB offsets)
    for (int w = wid; w < WW; w += 16) {
        float m = 0.f;
        for (int i = lane; i < PP; i += 64) m = fmaxf(m, corr[w * CSTRIDE + i]);
        m = fmaxf(m, __shfl_xor(m, 1));
        m = fmaxf(m, __shfl_xor(m, 2));
        m = fmaxf(m, __shfl_xor(m, 4));
        m = fmaxf(m, __shfl_xor(m, 8));
        m = fmaxf(m, __shfl_xor(m, 16));
        m = fmaxf(m, __shfl_xor(m, 32));
        float s = 0.f;
        for (int i = lane; i < PP; i += 64) {
            float e = __expf(EXPK * (corr[w * CSTRIDE + i] - m));
            s += e;
            corr[w * CSTRIDE + i] = e;  // cache exp for write phase
        }
        s += __shfl_xor(s, 1);
        s += __shfl_xor(s, 2);
        s += __shfl_xor(s, 4);
        s += __shfl_xor(s, 8);
        s += __shfl_xor(s, 16);
        s += __shfl_xor(s, 32);
        if (lane == 0) is_lds[w] = 1.0f / s;
    }
    __syncthreads();

    // masked write: out[bt][i=dh*25+dw][h][w]; idx padded to 32 per i; NT stores
    float* obase = out + (size_t)bt * PP * HWD + h * WW;
    for (int idx = tid; idx < PP * 32; idx += 1024) {
        int w = idx & 31;
        if (w < 30) {
            int i = idx >> 5;
            int dh = i / 25, dw = i - dh * 25;
            bool valid = ((unsigned)(h + dh - RR) < (unsigned)HH) &&
                         ((unsigned)(w + dw - RR) < (unsigned)WW);
            float val = -1.0f;
            if (valid) val = corr[w * CSTRIDE + i] * is_lds[w];
            __builtin_nontemporal_store(val, &obase[(size_t)i * HWD + w]);
        }
    }
}

extern "C" void kernel_launch(void* const* d_in, const int* in_sizes, int n_in,
                              void* d_out, int out_size, void* d_ws, size_t ws_size,
                              hipStream_t stream) {
    const float* feat1 = (const float*)d_in[0];  // video [8,512,4,30,30]
    const float* feat2 = (const float*)d_in[1];  // patch [8,512,30,30]
    float* out = (float*)d_out;
    unsigned char* Apk = (unsigned char*)d_ws;                   // [8*30][32 KB]
    unsigned char* Bpk = Apk + (size_t)BD * 30 * ROWPKB;         // [32*30][32 KB]

    norm_pack_kernel<<<dim3(30, 40), 256, 0, stream>>>(feat2, feat1, Apk, Bpk);
    corr_kernel<<<dim3(960), 1024, 0, stream>>>(Apk, Bpk, out);
}

// Round 14
// 101.664 us; speedup vs baseline: 2.0760x; 2.0760x over previous
//
#include <hip/hip_runtime.h>

#define RR 12
#define PD 25
#define PP 625
#define HH 30
#define WW 30
#define HWD 900
#define CD 512
#define BD 8
#define TD 4
#define CSTRIDE 628            // 625 + 3 pad
#define ROWPKB 32768           // BYTES per packed (plane,row): 16ks * 2piece * 64lane * 16B
#define QSCALE 16129.0f        // 127*127
#define EXPK (512.0f / QSCALE) // folded exp scale

typedef __attribute__((ext_vector_type(4))) int i32x4;
typedef __attribute__((ext_vector_type(16))) int i32x16;

// relu + L2-normalize over C, then quantize to 2-piece int8 fixed point:
//   a ~= (A1 + A2/254)/127,  A1 in [0,127], A2 in [-127,127]
// packed in 32x32x32-i8 MFMA fragment-major layout:
//   [plane][row][ks(16)][piece(2)][lane(64)][16 bytes]
//   element (pix x = lane&31, k = ks*32 + (lane>>5)*16 + j)
// 1D grid 1200, XCD-chunked: idx=(gid&7)*150+(gid>>3); plane=idx/30 row=idx%30
// so adjacent rows of a plane co-reside on one XCD (L2 absorbs 120-B line splits).
// plane 0..7: patch -> outA ; plane 8..39: video bt -> outB
__global__ __launch_bounds__(512) void norm_pack_kernel(const float* __restrict__ inP,
                                                        const float* __restrict__ inV,
                                                        unsigned char* __restrict__ outA,
                                                        unsigned char* __restrict__ outB) {
    int idx = ((blockIdx.x & 7) * 150) + (blockIdx.x >> 3);
    int plane = idx / 30;
    int row = idx - plane * 30;
    const float* in;
    size_t base;
    int c_stride;
    unsigned char* ob;
    if (plane < 8) {
        in = inP; c_stride = HWD;
        base = (size_t)plane * CD * HWD + row * WW;
        ob = outA + (size_t)(plane * 30 + row) * ROWPKB;
    } else {
        int bt = plane - 8;
        int b = bt >> 2, t = bt & 3;
        in = inV; c_stride = TD * HWD;
        base = (size_t)b * CD * (TD * HWD) + (size_t)t * HWD + row * WW;
        ob = outB + (size_t)(bt * 30 + row) * ROWPKB;
    }
    __shared__ float tile[30][516];
    __shared__ float inv[30];
    int tid = threadIdx.x;
    // float2 loads: 30 pixels = 15 float2 per c-row (8-B aligned)
    for (int it = 0; it < 16; ++it) {
        int lin = it * 512 + tid;     // 8192 slots = 512 c * 16 pg (pg 15 idle)
        int c = lin >> 4, pg = lin & 15;
        if (pg < 15) {
            const float2 v = *reinterpret_cast<const float2*>(
                &in[base + (size_t)c * c_stride + pg * 2]);
            tile[pg * 2][c] = fmaxf(v.x, 0.f);
            tile[pg * 2 + 1][c] = fmaxf(v.y, 0.f);
        }
    }
    __syncthreads();
    if ((tid >> 3) < 30) {
        int p = tid >> 3, s8 = tid & 7;
        float acc = 0.f;
#pragma unroll
        for (int j = 0; j < 16; ++j) {
            const float4 v = *reinterpret_cast<const float4*>(&tile[p][(s8 + j * 8) * 4]);
            acc += v.x * v.x + v.y * v.y + v.z * v.z + v.w * v.w;
        }
        acc += __shfl_xor(acc, 1);
        acc += __shfl_xor(acc, 2);
        acc += __shfl_xor(acc, 4);
        if (s8 == 0) inv[p] = 1.0f / fmaxf(sqrtf(acc), 1e-12f);
    }
    __syncthreads();
    for (int sl = tid; sl < 1024; sl += 512) {   // sl = ks*64 + lane
        int ks = sl >> 6, ln = sl & 63;
        int x = ln & 31;
        if (x > 29) x = 29;                       // pad lanes (guarded in corr)
        int kb = ks * 32 + (ln >> 5) * 16;
        float iv = inv[x];
        union { signed char c[16]; i32x4 v; } p1, p2;
#pragma unroll
        for (int j = 0; j < 16; ++j) {
            float nv = tile[x][kb + j] * iv;      // in [0,1]
            float s1 = rintf(nv * 127.f);
            float r = nv * 127.f - s1;
            float s2 = rintf(r * 254.f);
            p1.c[j] = (signed char)(int)s1;
            p2.c[j] = (signed char)(int)s2;
        }
        *(i32x4*)(ob + (size_t)ks * 2048 + ln * 16) = p1.v;
        *(i32x4*)(ob + (size_t)ks * 2048 + 1024 + ln * 16) = p2.v;
    }
}

// 1D grid of 960, XCD-bijective swizzle: xcd r owns b=r (bt in 4r..4r+3, h-major
// within bt). 1024 thr = 16 waves; wave owns dh slots (stride 16). A-row staged
// in LDS (32 KB); B streamed from XCD-local L2. v_mfma_i32_32x32x32_i8, 4 chains.
// Output written with NON-TEMPORAL stores so the 72 MB stream doesn't evict B from L2.
__global__ __launch_bounds__(1024, 4) void corr_kernel(
    const unsigned char* __restrict__ Apk, const unsigned char* __restrict__ Bpk,
    float* __restrict__ out) {
    int gid = blockIdx.x;
    int r = gid & 7;          // target XCD
    int x_ = gid >> 3;        // 0..119
    int btl = x_ / 30;
    int h = x_ - btl * 30;
    int bt = r * 4 + btl;
    int b = r;

    __shared__ __attribute__((aligned(16))) float corr[HH * CSTRIDE];
    __shared__ unsigned char alds[ROWPKB];
    __shared__ float is_lds[HH];
    int tid = threadIdx.x;
    int wid = tid >> 6, lane = tid & 63;

    {
        float4 z = {0.f, 0.f, 0.f, 0.f};
        float4* cz = (float4*)corr;
        for (int i = tid; i < (HH * CSTRIDE) / 4; i += 1024) cz[i] = z;
    }
    // stage A row (32 KB) into LDS, linear copy
    {
        const uint4* src = (const uint4*)(Apk + (size_t)(b * 30 + h) * ROWPKB);
        uint4* dst = (uint4*)alds;
#pragma unroll
        for (int i = 0; i < 2; ++i) dst[i * 1024 + tid] = src[i * 1024 + tid];
    }
    const unsigned char* bplane = Bpk + (size_t)bt * 30 * ROWPKB + lane * 16;
    int dh_lo = max(0, RR - h);
    int dh_hi = min(PD - 1, HH - 1 + RR - h);
    __syncthreads();  // corr zeroed + A staged

    const unsigned char* albase = alds + lane * 16;
    for (int dh = dh_lo + wid; dh <= dh_hi; dh += 16) {
        int y = h + dh - RR;
        const unsigned char* bbase = bplane + (size_t)y * ROWPKB;
        i32x16 s11, s12, s21, s22;
#pragma unroll
        for (int i = 0; i < 16; ++i) { s11[i] = 0; s12[i] = 0; s21[i] = 0; s22[i] = 0; }
#pragma unroll 8
        for (int ks = 0; ks < 16; ++ks) {
            i32x4 a1 = *(const i32x4*)(albase + ks * 2048);
            i32x4 a2 = *(const i32x4*)(albase + ks * 2048 + 1024);
            i32x4 b1 = *(const i32x4*)(bbase + ks * 2048);
            i32x4 b2 = *(const i32x4*)(bbase + ks * 2048 + 1024);
            s11 = __builtin_amdgcn_mfma_i32_32x32x32_i8(a1, b1, s11, 0, 0, 0);
            s12 = __builtin_amdgcn_mfma_i32_32x32x32_i8(a1, b2, s12, 0, 0, 0);
            s21 = __builtin_amdgcn_mfma_i32_32x32x32_i8(a2, b1, s21, 0, 0, 0);
            s22 = __builtin_amdgcn_mfma_i32_32x32x32_i8(a2, b2, s22, 0, 0, 0);
        }
        int x = lane & 31;
        if (x < 30) {
            int rbase = 4 * (lane >> 5);
#pragma unroll
            for (int rr = 0; rr < 16; ++rr) {
                int w = (rr & 3) + 8 * (rr >> 2) + rbase;  // C layout: col=lane&31
                int dw = x - w + RR;
                if (w < 30 && (unsigned)dw < (unsigned)PD) {
                    // corr scaled by QSCALE (folded into EXPK)
                    float c = fmaf((float)(s12[rr] + s21[rr]), 1.0f / 254.0f,
                                   (float)s11[rr]) +
                              (float)s22[rr] * (1.0f / 64516.0f);
                    corr[w * CSTRIDE + dh * PD + dw] = c;
                }
            }
        }
    }
    __syncthreads();

    // per-pixel softmax over 625 offsets (zeros present for OOB offsets)
    for (int w = wid; w < WW; w += 16) {
        float m = 0.f;
        for (int i = lane; i < PP; i += 64) m = fmaxf(m, corr[w * CSTRIDE + i]);
        m = fmaxf(m, __shfl_xor(m, 1));
        m = fmaxf(m, __shfl_xor(m, 2));
        m = fmaxf(m, __shfl_xor(m, 4));
        m = fmaxf(m, __shfl_xor(m, 8));
        m = fmaxf(m, __shfl_xor(m, 16));
        m = fmaxf(m, __shfl_xor(m, 32));
        float s = 0.f;
        for (int i = lane; i < PP; i += 64) {
            float e = __expf(EXPK * (corr[w * CSTRIDE + i] - m));
            s += e;
            corr[w * CSTRIDE + i] = e;  // cache exp for write phase
        }
        s += __shfl_xor(s, 1);
        s += __shfl_xor(s, 2);
        s += __shfl_xor(s, 4);
        s += __shfl_xor(s, 8);
        s += __shfl_xor(s, 16);
        s += __shfl_xor(s, 32);
        if (lane == 0) is_lds[w] = 1.0f / s;
    }
    __syncthreads();

    // masked write: out[bt][i=dh*25+dw][h][w]; idx padded to 32 per i; NT stores
    float* obase = out + (size_t)bt * PP * HWD + h * WW;
    for (int idx = tid; idx < PP * 32; idx += 1024) {
        int w = idx & 31;
        if (w < 30) {
            int i = idx >> 5;
            int dh = i / 25, dw = i - dh * 25;
            bool valid = ((unsigned)(h + dh - RR) < (unsigned)HH) &&
                         ((unsigned)(w + dw - RR) < (unsigned)WW);
            float val = -1.0f;
            if (valid) val = corr[w * CSTRIDE + i] * is_lds[w];
            __builtin_nontemporal_store(val, &obase[(size_t)i * HWD + w]);
        }
    }
}

extern "C" void kernel_launch(void* const* d_in, const int* in_sizes, int n_in,
                              void* d_out, int out_size, void* d_ws, size_t ws_size,
                              hipStream_t stream) {
    const float* feat1 = (const float*)d_in[0];  // video [8,512,4,30,30]
    const float* feat2 = (const float*)d_in[1];  // patch [8,512,30,30]
    float* out = (float*)d_out;
    unsigned char* Apk = (unsigned char*)d_ws;                   // [8*30][32 KB]
    unsigned char* Bpk = Apk + (size_t)BD * 30 * ROWPKB;         // [32*30][32 KB]

    norm_pack_kernel<<<dim3(1200), 512, 0, stream>>>(feat2, feat1, Apk, Bpk);
    corr_kernel<<<dim3(960), 1024, 0, stream>>>(Apk, Bpk, out);
}